// Round 9
// baseline (701.970 us; speedup 1.0000x reference)
//
#include <hip/hip_runtime.h>
#include <hip/hip_bf16.h>

// ---------------------------------------------------------------------------
// ProjectedConjugatedCSPNet: LN -> edge MLP (gather+sinemb+2xGEMM+silu) ->
// scatter-mean -> node MLP (2xGEMM+silu) -> residual add.
// R9: grid-balance + VALU-diet.
//  - ln_kernel split back out (10000 blocks); hab_gemm M=32 grid(313,2)
//    (~2.5 blocks/CU, 4 resident) — R8's 157-block ln_hab starved the chip.
//  - edge_mlp epilogue: e2 stored bf16 in slab (64x512 fits), ONE 512-thread
//    segment-reduce pass (col/thread, 64 rows), wave-uniform 2KB atomic
//    flushes; one barrier pair and half the reduce iterations removed.
//  - rest = R8: permuted HAp/HBp/LATBp direct-load acc-init, interleaved
//    sin/cos staging, rotated B-prefetch kloop.
// ---------------------------------------------------------------------------

#include <type_traits>

typedef __attribute__((ext_vector_type(8))) short bfrag;   // 8 bf16 = 4 VGPRs
typedef __attribute__((ext_vector_type(4))) float ffrag;   // 4 fp32 acc

#define DEVI __device__ __forceinline__

constexpr int N_NODES = 10000;
constexpr int N_EDGES = 200000;
constexpr int HD      = 512;       // hidden dim
constexpr int NT      = HD / 16;   // 32 n-tiles of 16 cols
constexpr int SLABW   = 520;       // slab row stride in ushorts (1040 B)
constexpr int KSTR    = NT * 64 * 8;  // B ktile stride in ushorts (16384)

DEVI float silu_f(float v) { return v / (1.0f + __expf(-v)); }

DEVI ushort f2bf(float f) {
    unsigned u = __float_as_uint(f);
    unsigned r = (u + 0x7fffu + ((u >> 16) & 1u)) >> 16;
    return (ushort)r;
}
DEVI float bf2f(ushort v) { return __uint_as_float((unsigned)v << 16); }

// permuted C-fragment column index: col (w*64+16n+ml) stored at (w*64+ml*4+n)
DEVI int cperm(int col) {
    return (col & ~63) | ((col & 15) << 2) | ((col >> 4) & 3);
}

// ------- Weight swizzle: W[K x 512] fp32 -> B-fragment-linear bf16 ----------
// mode 0: identity rows. mode 3: sin/cos interleaved K=768:
//   krow -> d=krow>>8, rm=krow&255, k=rm>>1, src=(rm&1?1414:1030)+d*128+k
__global__ void wswz_kernel(const float* __restrict__ W, ushort* __restrict__ dst,
                            int Kp, int mode) {
    int fid = blockIdx.x * blockDim.x + threadIdx.x;
    int total = (Kp / 32) * NT * 64;
    if (fid >= total) return;
    int l  = fid & 63;
    int nn = (fid >> 6) & 31;
    int kk = fid >> 11;
    int col = nn * 16 + (l & 15);
    int kb  = kk * 32 + (l >> 4) * 8;
    union { ushort u16[8]; uint4 u4; } v;
    for (int j = 0; j < 8; ++j) {
        int krow = kb + j;
        int src;
        if (mode == 3) {
            int d = krow >> 8, rm = krow & 255, k = rm >> 1;
            src = ((rm & 1) ? 1414 : 1030) + d * 128 + k;
        } else {
            src = krow;
        }
        v.u16[j] = f2bf(W[(size_t)src * HD + col]);
    }
    *(uint4*)(dst + (size_t)fid * 8) = v.u4;
}

// ---------------- LayerNorm: node_features -> h (bf16) ----------------------
__global__ void ln_kernel(const float* __restrict__ x, const float* __restrict__ g,
                          const float* __restrict__ b, ushort* __restrict__ h) {
    __shared__ float wred[8];
    __shared__ float mb[2];
    int row = blockIdx.x;
    int t = threadIdx.x;              // 256 threads
    const float* xr = x + (size_t)row * HD;
    float x0 = xr[t], x1 = xr[t + 256];
    float s = x0 + x1, q = x0 * x0 + x1 * x1;
    for (int o = 32; o; o >>= 1) { s += __shfl_down(s, o); q += __shfl_down(q, o); }
    int w = t >> 6, l = t & 63;
    if (l == 0) { wred[w] = s; wred[w + 4] = q; }
    __syncthreads();
    if (t == 0) {
        float S = wred[0] + wred[1] + wred[2] + wred[3];
        float Q = wred[4] + wred[5] + wred[6] + wred[7];
        float m = S * (1.0f / HD);
        float v = Q * (1.0f / HD) - m * m;
        mb[0] = m; mb[1] = rsqrtf(v + 1e-5f);
    }
    __syncthreads();
    float m = mb[0], rs = mb[1];
    h[(size_t)row * HD + t]       = f2bf((x0 - m) * rs * g[t] + b[t]);
    h[(size_t)row * HD + t + 256] = f2bf((x1 - m) * rs * g[t + 256] + b[t + 256]);
}

// ---------------- LATB: per-graph lat*W1_lat + b1, permuted fp32 ------------
__global__ void latb_kernel(const float* __restrict__ latt, const float* __restrict__ W_e1,
                            const float* __restrict__ b1, float* __restrict__ LATBp) {
    int g = blockIdx.x;           // 50 graphs
    int t = threadIdx.x;          // 512 cols
    float a = b1[t];
    for (int c = 0; c < 6; ++c)
        a += latt[g * 6 + c] * W_e1[(size_t)(1024 + c) * HD + t];
    LATBp[(size_t)g * HD + cperm(t)] = a;
}

// ---------------- zero c32 + agg --------------------------------------------
__global__ void zero_kernel(int* __restrict__ c32, float* __restrict__ agg) {
    int i = blockIdx.x * 256 + threadIdx.x;     // N_NODES*HD threads
    if (i < N_NODES) c32[i] = 0;
    agg[i] = 0.0f;
}

// ---------------- CSR build -------------------------------------------------
__global__ void hist_kernel(const int* __restrict__ eidx, int* __restrict__ cnt32) {
    int e = blockIdx.x * 256 + threadIdx.x;
    if (e < N_EDGES) atomicAdd(&cnt32[eidx[e]], 1);
}

__global__ void scan_kernel(const int* __restrict__ cnt32, int* __restrict__ row_ptr,
                            int* __restrict__ cursor) {
    __shared__ int buf[1024];
    int t = threadIdx.x;              // 1024 threads
    int base = t * 10;
    int loc[10]; int s = 0;
    for (int i = 0; i < 10; ++i) {
        int idx = base + i;
        int v = (idx < N_NODES) ? cnt32[idx] : 0;
        loc[i] = s; s += v;
    }
    buf[t] = s; __syncthreads();
    for (int off = 1; off < 1024; off <<= 1) {
        int v = 0; if (t >= off) v = buf[t - off];
        __syncthreads();
        buf[t] += v; __syncthreads();
    }
    int excl = buf[t] - s;
    for (int i = 0; i < 10; ++i) {
        int idx = base + i;
        if (idx < N_NODES) { int p = excl + loc[i]; row_ptr[idx] = p; cursor[idx] = p; }
    }
    if (t == 0) row_ptr[N_NODES] = N_EDGES;
}

__global__ void csr_fill(const int* __restrict__ eidx, int* __restrict__ cursor,
                         int* __restrict__ ebuf) {
    int e = blockIdx.x * 256 + threadIdx.x;
    if (e >= N_EDGES) return;
    int pos = atomicAdd(&cursor[eidx[e]], 1);
    ebuf[pos] = e;
}

// ---------------- agg (fp32) / deg -> aggb (bf16) ---------------------------
__global__ void aggdiv_kernel(const float* __restrict__ agg, const int* __restrict__ rp,
                              ushort* __restrict__ aggb) {
    int i = blockIdx.x * 256 + threadIdx.x;
    int row = i >> 9;
    int deg = rp[row + 1] - rp[row];
    float rc = 1.0f / (float)max(deg, 1);
    aggb[i] = f2bf(agg[i] * rc);
}

__global__ void sentinel_kernel(float* o, int n) {
    int i = blockIdx.x * 256 + threadIdx.x;
    if (i < n) o[i] = 123456789.0f;
}

// ---------------- rotated-prefetch kloop ------------------------------------
// n-outer MFMA groups; b_[n] reloaded for ktile p+1 right after consumption.
template <int KTN, int MT>
DEVI void kloop_rot(ffrag (&acc)[MT][4], const ushort* sl, const ushort* bp0,
                    int ml, int q) {
    bfrag b_[4];
    const ushort* bp = bp0;
    #pragma unroll
    for (int n = 0; n < 4; ++n) b_[n] = *(const bfrag*)(bp + n * 512);
    #pragma unroll
    for (int p = 0; p < KTN; ++p) {
        bfrag a_[MT];
        #pragma unroll
        for (int m = 0; m < MT; ++m)
            a_[m] = *(const bfrag*)&sl[(16 * m + ml) * SLABW + p * 32 + q * 8];
        const ushort* bpn = bp + KSTR;
        #pragma unroll
        for (int n = 0; n < 4; ++n) {
            #pragma unroll
            for (int m = 0; m < MT; ++m)
                acc[m][n] = __builtin_amdgcn_mfma_f32_16x16x32_bf16(a_[m], b_[n], acc[m][n], 0, 0, 0);
            if (p + 1 < KTN) b_[n] = *(const bfrag*)(bpn + n * 512);
        }
        bp = bpn;
    }
}

// ---------------- HA/HB producer (32 nodes x 512 per block, grid.y=A/B) -----
__global__ __launch_bounds__(512, 4) void hab_gemm(
    const ushort* __restrict__ h, const ushort* __restrict__ w1a_s,
    const ushort* __restrict__ w1b_s, ushort* __restrict__ HAp,
    ushort* __restrict__ HBp) {

    __shared__ __align__(16) ushort slab[32 * SLABW];   // 33 KB
    const int t = threadIdx.x;
    const int w = t >> 6;
    const int l = t & 63;
    const int q = l >> 4;
    const int ml = l & 15;
    const int rowbase = blockIdx.x * 32;
    const ushort* Bswz = blockIdx.y ? w1b_s : w1a_s;
    ushort* out = blockIdx.y ? HBp : HAp;

    // stage 32 rows: wave w loads rows w*4..w*4+3
    for (int j = 0; j < 4; ++j) {
        int rr = w * 4 + j;
        int row = rowbase + rr;
        if (row >= N_NODES) row = N_NODES - 1;
        *(uint4*)&slab[rr * SLABW + l * 8] =
            *(const uint4*)(h + (size_t)row * HD + l * 8);
    }
    __syncthreads();

    ffrag acc[2][4];
    for (int m = 0; m < 2; ++m)
        for (int n = 0; n < 4; ++n)
            acc[m][n] = (ffrag){0.f, 0.f, 0.f, 0.f};

    kloop_rot<16, 2>(acc, slab, Bswz + ((size_t)(w << 2) * 64 + l) * 8, ml, q);

    for (int m = 0; m < 2; ++m)
        for (int rr = 0; rr < 4; ++rr) {
            int grow = rowbase + 16 * m + 4 * q + rr;
            if (grow < N_NODES) {
                ushort4 v = make_ushort4(f2bf(acc[m][0][rr]), f2bf(acc[m][1][rr]),
                                         f2bf(acc[m][2][rr]), f2bf(acc[m][3][rr]));
                *(ushort4*)(out + (size_t)grow * HD + w * 64 + ml * 4) = v;
            }
        }
}

// ---------------- Fused edge MLP (64 edges x 512 cols per block) ------------
// acc = HAp[src] + HBp[dst] + LATBp[graph] (direct permuted loads);
// K-loop: 768 interleaved sin/cos (2 phases x 12 ktiles) with w1c;
// silu -> slab -> GEMM2(w2s) -> silu+b2 -> bf16 slab -> single-pass
// 512-thread CSR segment reduce -> atomic agg.
__global__ __launch_bounds__(512, 4) void edge_mlp(
    const ushort* __restrict__ HAp,   const ushort* __restrict__ HBp,
    const float* __restrict__ LATBp,  const ushort* __restrict__ w1c,
    const ushort* __restrict__ w2s,   const float* __restrict__ b2,
    float* __restrict__ agg,
    const int* __restrict__ edge_index, const int* __restrict__ e2g,
    const float* __restrict__ frac_diff, const int* __restrict__ ebuf) {

    __shared__ __align__(16) ushort slab[64 * SLABW];     // 66560 B
    __shared__ int   ssrc[64];
    __shared__ int   sdst[64];
    __shared__ int   sgrp[64];
    __shared__ float sfd[64 * 3];

    const int t = threadIdx.x;        // 512 threads = 8 waves
    const int w = t >> 6;
    const int l = t & 63;
    const int q = l >> 4;
    const int ml = l & 15;
    const int rowbase = blockIdx.x * 64;

    if (t < 64) {
        int eid = ebuf[rowbase + t];
        ssrc[t] = edge_index[eid];
        sdst[t] = edge_index[N_EDGES + eid];
        sgrp[t] = e2g[eid];
        for (int c = 0; c < 3; ++c) sfd[t * 3 + c] = frac_diff[(size_t)eid * 3 + c];
    }
    __syncthreads();

    // ---- acc init: direct permuted loads (L2-hot) ----
    ffrag acc[4][4];
    {
        const int cb = w * 64 + ml * 4;
        for (int m = 0; m < 4; ++m)
            for (int rr = 0; rr < 4; ++rr) {
                int rowl = 16 * m + 4 * q + rr;
                ushort4 a4 = *(const ushort4*)(HAp + (size_t)ssrc[rowl] * HD + cb);
                ushort4 h4 = *(const ushort4*)(HBp + (size_t)sdst[rowl] * HD + cb);
                float4  l4 = *(const float4*)(LATBp + (size_t)sgrp[rowl] * HD + cb);
                acc[m][0][rr] = bf2f(a4.x) + bf2f(h4.x) + l4.x;
                acc[m][1][rr] = bf2f(a4.y) + bf2f(h4.y) + l4.y;
                acc[m][2][rr] = bf2f(a4.z) + bf2f(h4.z) + l4.z;
                acc[m][3][rr] = bf2f(a4.w) + bf2f(h4.w) + l4.w;
            }
    }

    const int r  = t >> 3;            // staging row 0..63
    const int c0 = (t & 7) * 4;       // staging col 0..28 step 4
    float fd3[3] = { sfd[r * 3 + 0], sfd[r * 3 + 1], sfd[r * 3 + 2] };

    // ---- sin/cos staging: cols = interleaved (sin_k, cos_k) pairs ----
    auto stage = [&](int phase) {
        for (int i = 0; i < 12; ++i) {
            int c = c0 + 32 * i;                 // 0..380
            int cp = phase * 384 + c;            // global C-col
            int d = cp >> 8;
            float x = fd3[d];
            int k0 = (cp & 255) >> 1;
            float f0 = (float)k0 * x;
            float f1 = f0 + x;
            float r0 = __builtin_amdgcn_fractf(f0);
            float r1 = __builtin_amdgcn_fractf(f1);
            union { __hip_bfloat162 h2[2]; ushort4 u4; } pk;
            pk.h2[0] = __float22bfloat162_rn(float2{__builtin_amdgcn_sinf(r0),
                                                    __builtin_amdgcn_cosf(r0)});
            pk.h2[1] = __float22bfloat162_rn(float2{__builtin_amdgcn_sinf(r1),
                                                    __builtin_amdgcn_cosf(r1)});
            *(ushort4*)&slab[r * SLABW + c] = pk.u4;
        }
    };

    const ushort* bpw1 = w1c + ((size_t)(w << 2) * 64 + l) * 8;
    const ushort* bpw2 = w2s + ((size_t)(w << 2) * 64 + l) * 8;

    stage(0);
    __syncthreads();
    kloop_rot<12, 4>(acc, slab, bpw1, ml, q);
    __syncthreads();
    stage(1);
    __syncthreads();
    kloop_rot<12, 4>(acc, slab, bpw1 + (size_t)12 * KSTR, ml, q);
    __syncthreads();

    // ---- e1 = silu(acc) -> slab (bf16, row-major); reset acc ----
    for (int n = 0; n < 4; ++n) {
        int cg = w * 64 + n * 16 + ml;
        for (int m = 0; m < 4; ++m)
            for (int rr = 0; rr < 4; ++rr) {
                int rowl = 16 * m + 4 * q + rr;
                slab[rowl * SLABW + cg] = f2bf(silu_f(acc[m][n][rr]));
            }
    }
    for (int m = 0; m < 4; ++m)
        for (int n = 0; n < 4; ++n)
            acc[m][n] = (ffrag){0.f, 0.f, 0.f, 0.f};
    __syncthreads();

    // ---- GEMM2 straight from the slab ----
    kloop_rot<16, 4>(acc, slab, bpw2, ml, q);
    __syncthreads();                     // slab A-reads done

    // ---- e2 = silu(acc + b2) -> slab (bf16, row-major) ----
    for (int n = 0; n < 4; ++n) {
        int cg = w * 64 + n * 16 + ml;
        float bv = b2[cg];
        for (int m = 0; m < 4; ++m)
            for (int rr = 0; rr < 4; ++rr) {
                int rowl = 16 * m + 4 * q + rr;
                slab[rowl * SLABW + cg] = f2bf(silu_f(acc[m][n][rr] + bv));
            }
    }
    __syncthreads();

    // ---- single-pass CSR run-length segment reduce: col t, 64 rows ----
    {
        int cur = ssrc[0];
        float run = 0.f;
        for (int rr2 = 0; rr2 < 64; ++rr2) {
            int nd = ssrc[rr2];
            if (nd != cur) {
                unsafeAtomicAdd(&agg[(size_t)cur * HD + t], run);
                run = 0.f; cur = nd;
            }
            run += bf2f(slab[rr2 * SLABW + t]);
        }
        unsafeAtomicAdd(&agg[(size_t)cur * HD + t], run);
    }
}

// ---------------- Fused node MLP (64 nodes x 512 cols per block) ------------
__global__ __launch_bounds__(512, 4) void node_mlp(
    const ushort* __restrict__ h,     const ushort* __restrict__ aggb,
    const ushort* __restrict__ wn1s,  const ushort* __restrict__ wn2s,
    const float* __restrict__ b1,     const float* __restrict__ b2,
    const float* __restrict__ nf,     float* __restrict__ out) {

    __shared__ __align__(16) ushort slab[64 * SLABW];

    const int t = threadIdx.x;        // 512 threads = 8 waves
    const int w = t >> 6;
    const int l = t & 63;
    const int q = l >> 4;
    const int ml = l & 15;
    const int rowbase = blockIdx.x * 64;

    ffrag acc[4][4];
    for (int m = 0; m < 4; ++m)
        for (int n = 0; n < 4; ++n)
            acc[m][n] = (ffrag){0.f, 0.f, 0.f, 0.f};

    auto load_rows = [&](const ushort* base) {
        for (int j = 0; j < 8; ++j) {
            int rr = w * 8 + j;
            int row = rowbase + rr;
            if (row >= N_NODES) row = N_NODES - 1;
            *(uint4*)&slab[rr * SLABW + l * 8] =
                *(const uint4*)(base + (size_t)row * HD + l * 8);
        }
    };
    const ushort* bp1 = wn1s + ((size_t)(w << 2) * 64 + l) * 8;
    const ushort* bp2 = wn2s + ((size_t)(w << 2) * 64 + l) * 8;

    load_rows(h);                        __syncthreads();
    kloop_rot<16, 4>(acc, slab, bp1, ml, q);
    __syncthreads();
    load_rows(aggb);                     __syncthreads();
    kloop_rot<16, 4>(acc, slab, bp1 + (size_t)16 * KSTR, ml, q);
    __syncthreads();

    for (int n = 0; n < 4; ++n) {
        int cg = w * 64 + n * 16 + ml;
        float bv = b1[cg];
        for (int m = 0; m < 4; ++m)
            for (int rr = 0; rr < 4; ++rr) {
                int rowl = 16 * m + 4 * q + rr;
                slab[rowl * SLABW + cg] = f2bf(silu_f(acc[m][n][rr] + bv));
            }
    }
    for (int m = 0; m < 4; ++m)
        for (int n = 0; n < 4; ++n)
            acc[m][n] = (ffrag){0.f, 0.f, 0.f, 0.f};
    __syncthreads();

    kloop_rot<16, 4>(acc, slab, bp2, ml, q);

    for (int n = 0; n < 4; ++n) {
        int cg = w * 64 + n * 16 + ml;
        float bv = b2[cg];
        for (int m = 0; m < 4; ++m)
            for (int rr = 0; rr < 4; ++rr) {
                int rowl = 16 * m + 4 * q + rr;
                int row = rowbase + rowl;
                if (row < N_NODES) {
                    float v = silu_f(acc[m][n][rr] + bv);
                    out[(size_t)row * HD + cg] = nf[(size_t)row * HD + cg] + v;
                }
            }
    }
}

// ---------------------------------------------------------------------------
extern "C" void kernel_launch(void* const* d_in, const int* in_sizes, int n_in,
                              void* d_out, int out_size, void* d_ws, size_t ws_size,
                              hipStream_t stream) {
    const float* nf      = (const float*)d_in[0];
    const float* latt    = (const float*)d_in[1];
    const int*   eidx    = (const int*)d_in[2];
    const int*   e2g     = (const int*)d_in[3];
    const float* fd      = (const float*)d_in[4];
    const float* ln_g    = (const float*)d_in[6];
    const float* ln_b    = (const float*)d_in[7];
    const float* W_e1    = (const float*)d_in[8];
    const float* b_e1    = (const float*)d_in[9];
    const float* W_e2    = (const float*)d_in[10];
    const float* b_e2    = (const float*)d_in[11];
    const float* W_n1    = (const float*)d_in[12];
    const float* b_n1    = (const float*)d_in[13];
    const float* W_n2    = (const float*)d_in[14];
    const float* b_n2    = (const float*)d_in[15];
    float* out = (float*)d_out;

    auto al = [](size_t x) { return (x + 511) & ~(size_t)511; };
    size_t off_h    = 0;                         size_t sz_h    = (size_t)N_NODES * HD * 2;
    size_t off_w1a  = al(off_h + sz_h);          size_t sz_w1a  = (size_t)HD * HD * 2;
    size_t off_w1b  = al(off_w1a + sz_w1a);      size_t sz_w1b  = (size_t)HD * HD * 2;
    size_t off_w1c  = al(off_w1b + sz_w1b);      size_t sz_w1c  = (size_t)768 * HD * 2;
    size_t off_w2   = al(off_w1c + sz_w1c);      size_t sz_w2   = (size_t)HD * HD * 2;
    size_t off_wn1  = al(off_w2 + sz_w2);        size_t sz_wn1  = (size_t)2 * HD * HD * 2;
    size_t off_wn2  = al(off_wn1 + sz_wn1);      size_t sz_wn2  = (size_t)HD * HD * 2;
    size_t off_ha   = al(off_wn2 + sz_wn2);      size_t sz_ha   = (size_t)N_NODES * HD * 2;
    size_t off_hb   = al(off_ha + sz_ha);        size_t sz_hb   = (size_t)N_NODES * HD * 2;
    size_t off_lb   = al(off_hb + sz_hb);        size_t sz_lb   = (size_t)50 * HD * 4;
    size_t off_agb  = al(off_lb + sz_lb);        size_t sz_agb  = (size_t)N_NODES * HD * 2;
    size_t off_c32  = al(off_agb + sz_agb);      size_t sz_c32  = (size_t)N_NODES * 4;
    size_t off_cur  = al(off_c32 + sz_c32);      size_t sz_cur  = (size_t)N_NODES * 4;
    size_t off_rp   = al(off_cur + sz_cur);      size_t sz_rp   = (size_t)(N_NODES + 1) * 4;
    size_t off_ebuf = al(off_rp + sz_rp);        size_t sz_ebuf = (size_t)N_EDGES * 4;
    size_t off_agg  = al(off_ebuf + sz_ebuf);    size_t sz_agg  = (size_t)N_NODES * HD * 4;
    size_t need     = off_agg + sz_agg;

    if (ws_size < need) {
        sentinel_kernel<<<(out_size + 255) / 256, 256, 0, stream>>>(out, out_size);
        return;
    }

    char* ws = (char*)d_ws;
    ushort* h     = (ushort*)(ws + off_h);
    ushort* w1a_s = (ushort*)(ws + off_w1a);
    ushort* w1b_s = (ushort*)(ws + off_w1b);
    ushort* w1c_s = (ushort*)(ws + off_w1c);
    ushort* w2s   = (ushort*)(ws + off_w2);
    ushort* wn1s  = (ushort*)(ws + off_wn1);
    ushort* wn2s  = (ushort*)(ws + off_wn2);
    ushort* HAp   = (ushort*)(ws + off_ha);
    ushort* HBp   = (ushort*)(ws + off_hb);
    float*  LATBp = (float*)(ws + off_lb);
    ushort* aggb  = (ushort*)(ws + off_agb);
    int*    c32   = (int*)(ws + off_c32);
    int*    cur   = (int*)(ws + off_cur);
    int*    rp    = (int*)(ws + off_rp);
    int*    ebuf  = (int*)(ws + off_ebuf);
    float*  agg   = (float*)(ws + off_agg);

    // prep
    zero_kernel<<<(N_NODES * HD) / 256, 256, 0, stream>>>(c32, agg);
    wswz_kernel<<<(HD / 32) * NT * 64 / 256, 256, 0, stream>>>(W_e1, w1a_s, HD, 0);
    wswz_kernel<<<(HD / 32) * NT * 64 / 256, 256, 0, stream>>>(W_e1 + (size_t)HD * HD, w1b_s, HD, 0);
    wswz_kernel<<<(768 / 32) * NT * 64 / 256, 256, 0, stream>>>(W_e1, w1c_s, 768, 3);
    wswz_kernel<<<(HD / 32) * NT * 64 / 256, 256, 0, stream>>>(W_e2, w2s, HD, 0);
    wswz_kernel<<<(2 * HD / 32) * NT * 64 / 256, 256, 0, stream>>>(W_n1, wn1s, 2 * HD, 0);
    wswz_kernel<<<(HD / 32) * NT * 64 / 256, 256, 0, stream>>>(W_n2, wn2s, HD, 0);
    latb_kernel<<<50, 512, 0, stream>>>(latt, W_e1, b_e1, LATBp);

    // CSR build (edges sorted by src node)
    hist_kernel<<<(N_EDGES + 255) / 256, 256, 0, stream>>>(eidx, c32);
    scan_kernel<<<1, 1024, 0, stream>>>(c32, rp, cur);
    csr_fill<<<(N_EDGES + 255) / 256, 256, 0, stream>>>(eidx, cur, ebuf);

    // LN then node-level hoist (HAp, HBp)
    ln_kernel<<<N_NODES, 256, 0, stream>>>(nf, ln_g, ln_b, h);
    hab_gemm<<<dim3(313, 2), 512, 0, stream>>>(h, w1a_s, w1b_s, HAp, HBp);

    // fused edge MLP (CSR order) -> agg
    edge_mlp<<<N_EDGES / 64, 512, 0, stream>>>(
        HAp, HBp, LATBp, w1c_s, w2s, b_e2, agg, eidx, e2g, fd, ebuf);

    // scatter-mean divide (deg from CSR)
    aggdiv_kernel<<<(N_NODES * HD) / 256, 256, 0, stream>>>(agg, rp, aggb);

    // fused node MLP
    int nblocks = (N_NODES + 63) / 64;
    node_mlp<<<nblocks, 512, 0, stream>>>(h, aggb, wn1s, wn2s, b_n1, b_n2, nf, out);
}

// Round 10
// 612.178 us; speedup vs baseline: 1.1467x; 1.1467x over previous
//
#include <hip/hip_runtime.h>
#include <hip/hip_bf16.h>

// ---------------------------------------------------------------------------
// ProjectedConjugatedCSPNet: LN -> edge MLP (gather+sinemb+2xGEMM+silu) ->
// scatter-mean -> node MLP (2xGEMM+silu) -> residual add.
// R10: combine the two measured winners.
//  - R9's producer split: ln_kernel (10000 blocks) + hab_gemm M=32 grid(313,2)
//    => "others" measured 222 us.
//  - R8's edge_mlp epilogue: two-half fp32 slab + 256-thread segment reduce
//    => edge_mlp measured 400 us (R9's single-pass bf16 reduce regressed to
//    480: rolled loop w/ conditional atomic defeats LDS-read pipelining).
//  - rest unchanged: permuted HAp/HBp/LATBp direct-load acc-init, interleaved
//    sin/cos staging, rotated B-prefetch kloop.
// ---------------------------------------------------------------------------

#include <type_traits>

typedef __attribute__((ext_vector_type(8))) short bfrag;   // 8 bf16 = 4 VGPRs
typedef __attribute__((ext_vector_type(4))) float ffrag;   // 4 fp32 acc

#define DEVI __device__ __forceinline__

constexpr int N_NODES = 10000;
constexpr int N_EDGES = 200000;
constexpr int HD      = 512;       // hidden dim
constexpr int NT      = HD / 16;   // 32 n-tiles of 16 cols
constexpr int SLABW   = 520;       // slab row stride in ushorts (1040 B)
constexpr int KSTR    = NT * 64 * 8;  // B ktile stride in ushorts (16384)

DEVI float silu_f(float v) { return v / (1.0f + __expf(-v)); }

DEVI ushort f2bf(float f) {
    unsigned u = __float_as_uint(f);
    unsigned r = (u + 0x7fffu + ((u >> 16) & 1u)) >> 16;
    return (ushort)r;
}
DEVI float bf2f(ushort v) { return __uint_as_float((unsigned)v << 16); }

// permuted C-fragment column index: col (w*64+16n+ml) stored at (w*64+ml*4+n)
DEVI int cperm(int col) {
    return (col & ~63) | ((col & 15) << 2) | ((col >> 4) & 3);
}

// ------- Weight swizzle: W[K x 512] fp32 -> B-fragment-linear bf16 ----------
// mode 0: identity rows. mode 3: sin/cos interleaved K=768:
//   krow -> d=krow>>8, rm=krow&255, k=rm>>1, src=(rm&1?1414:1030)+d*128+k
__global__ void wswz_kernel(const float* __restrict__ W, ushort* __restrict__ dst,
                            int Kp, int mode) {
    int fid = blockIdx.x * blockDim.x + threadIdx.x;
    int total = (Kp / 32) * NT * 64;
    if (fid >= total) return;
    int l  = fid & 63;
    int nn = (fid >> 6) & 31;
    int kk = fid >> 11;
    int col = nn * 16 + (l & 15);
    int kb  = kk * 32 + (l >> 4) * 8;
    union { ushort u16[8]; uint4 u4; } v;
    for (int j = 0; j < 8; ++j) {
        int krow = kb + j;
        int src;
        if (mode == 3) {
            int d = krow >> 8, rm = krow & 255, k = rm >> 1;
            src = ((rm & 1) ? 1414 : 1030) + d * 128 + k;
        } else {
            src = krow;
        }
        v.u16[j] = f2bf(W[(size_t)src * HD + col]);
    }
    *(uint4*)(dst + (size_t)fid * 8) = v.u4;
}

// ---------------- LayerNorm: node_features -> h (bf16) ----------------------
__global__ void ln_kernel(const float* __restrict__ x, const float* __restrict__ g,
                          const float* __restrict__ b, ushort* __restrict__ h) {
    __shared__ float wred[8];
    __shared__ float mb[2];
    int row = blockIdx.x;
    int t = threadIdx.x;              // 256 threads
    const float* xr = x + (size_t)row * HD;
    float x0 = xr[t], x1 = xr[t + 256];
    float s = x0 + x1, q = x0 * x0 + x1 * x1;
    for (int o = 32; o; o >>= 1) { s += __shfl_down(s, o); q += __shfl_down(q, o); }
    int w = t >> 6, l = t & 63;
    if (l == 0) { wred[w] = s; wred[w + 4] = q; }
    __syncthreads();
    if (t == 0) {
        float S = wred[0] + wred[1] + wred[2] + wred[3];
        float Q = wred[4] + wred[5] + wred[6] + wred[7];
        float m = S * (1.0f / HD);
        float v = Q * (1.0f / HD) - m * m;
        mb[0] = m; mb[1] = rsqrtf(v + 1e-5f);
    }
    __syncthreads();
    float m = mb[0], rs = mb[1];
    h[(size_t)row * HD + t]       = f2bf((x0 - m) * rs * g[t] + b[t]);
    h[(size_t)row * HD + t + 256] = f2bf((x1 - m) * rs * g[t + 256] + b[t + 256]);
}

// ---------------- LATB: per-graph lat*W1_lat + b1, permuted fp32 ------------
__global__ void latb_kernel(const float* __restrict__ latt, const float* __restrict__ W_e1,
                            const float* __restrict__ b1, float* __restrict__ LATBp) {
    int g = blockIdx.x;           // 50 graphs
    int t = threadIdx.x;          // 512 cols
    float a = b1[t];
    for (int c = 0; c < 6; ++c)
        a += latt[g * 6 + c] * W_e1[(size_t)(1024 + c) * HD + t];
    LATBp[(size_t)g * HD + cperm(t)] = a;
}

// ---------------- zero c32 + agg --------------------------------------------
__global__ void zero_kernel(int* __restrict__ c32, float* __restrict__ agg) {
    int i = blockIdx.x * 256 + threadIdx.x;     // N_NODES*HD threads
    if (i < N_NODES) c32[i] = 0;
    agg[i] = 0.0f;
}

// ---------------- CSR build -------------------------------------------------
__global__ void hist_kernel(const int* __restrict__ eidx, int* __restrict__ cnt32) {
    int e = blockIdx.x * 256 + threadIdx.x;
    if (e < N_EDGES) atomicAdd(&cnt32[eidx[e]], 1);
}

__global__ void scan_kernel(const int* __restrict__ cnt32, int* __restrict__ row_ptr,
                            int* __restrict__ cursor) {
    __shared__ int buf[1024];
    int t = threadIdx.x;              // 1024 threads
    int base = t * 10;
    int loc[10]; int s = 0;
    for (int i = 0; i < 10; ++i) {
        int idx = base + i;
        int v = (idx < N_NODES) ? cnt32[idx] : 0;
        loc[i] = s; s += v;
    }
    buf[t] = s; __syncthreads();
    for (int off = 1; off < 1024; off <<= 1) {
        int v = 0; if (t >= off) v = buf[t - off];
        __syncthreads();
        buf[t] += v; __syncthreads();
    }
    int excl = buf[t] - s;
    for (int i = 0; i < 10; ++i) {
        int idx = base + i;
        if (idx < N_NODES) { int p = excl + loc[i]; row_ptr[idx] = p; cursor[idx] = p; }
    }
    if (t == 0) row_ptr[N_NODES] = N_EDGES;
}

__global__ void csr_fill(const int* __restrict__ eidx, int* __restrict__ cursor,
                         int* __restrict__ ebuf) {
    int e = blockIdx.x * 256 + threadIdx.x;
    if (e >= N_EDGES) return;
    int pos = atomicAdd(&cursor[eidx[e]], 1);
    ebuf[pos] = e;
}

// ---------------- agg (fp32) / deg -> aggb (bf16) ---------------------------
__global__ void aggdiv_kernel(const float* __restrict__ agg, const int* __restrict__ rp,
                              ushort* __restrict__ aggb) {
    int i = blockIdx.x * 256 + threadIdx.x;
    int row = i >> 9;
    int deg = rp[row + 1] - rp[row];
    float rc = 1.0f / (float)max(deg, 1);
    aggb[i] = f2bf(agg[i] * rc);
}

__global__ void sentinel_kernel(float* o, int n) {
    int i = blockIdx.x * 256 + threadIdx.x;
    if (i < n) o[i] = 123456789.0f;
}

// ---------------- rotated-prefetch kloop ------------------------------------
// n-outer MFMA groups; b_[n] reloaded for ktile p+1 right after consumption.
template <int KTN, int MT>
DEVI void kloop_rot(ffrag (&acc)[MT][4], const ushort* sl, const ushort* bp0,
                    int ml, int q) {
    bfrag b_[4];
    const ushort* bp = bp0;
    #pragma unroll
    for (int n = 0; n < 4; ++n) b_[n] = *(const bfrag*)(bp + n * 512);
    #pragma unroll
    for (int p = 0; p < KTN; ++p) {
        bfrag a_[MT];
        #pragma unroll
        for (int m = 0; m < MT; ++m)
            a_[m] = *(const bfrag*)&sl[(16 * m + ml) * SLABW + p * 32 + q * 8];
        const ushort* bpn = bp + KSTR;
        #pragma unroll
        for (int n = 0; n < 4; ++n) {
            #pragma unroll
            for (int m = 0; m < MT; ++m)
                acc[m][n] = __builtin_amdgcn_mfma_f32_16x16x32_bf16(a_[m], b_[n], acc[m][n], 0, 0, 0);
            if (p + 1 < KTN) b_[n] = *(const bfrag*)(bpn + n * 512);
        }
        bp = bpn;
    }
}

// ---------------- HA/HB producer (32 nodes x 512 per block, grid.y=A/B) -----
__global__ __launch_bounds__(512, 4) void hab_gemm(
    const ushort* __restrict__ h, const ushort* __restrict__ w1a_s,
    const ushort* __restrict__ w1b_s, ushort* __restrict__ HAp,
    ushort* __restrict__ HBp) {

    __shared__ __align__(16) ushort slab[32 * SLABW];   // 33 KB
    const int t = threadIdx.x;
    const int w = t >> 6;
    const int l = t & 63;
    const int q = l >> 4;
    const int ml = l & 15;
    const int rowbase = blockIdx.x * 32;
    const ushort* Bswz = blockIdx.y ? w1b_s : w1a_s;
    ushort* out = blockIdx.y ? HBp : HAp;

    // stage 32 rows: wave w loads rows w*4..w*4+3
    for (int j = 0; j < 4; ++j) {
        int rr = w * 4 + j;
        int row = rowbase + rr;
        if (row >= N_NODES) row = N_NODES - 1;
        *(uint4*)&slab[rr * SLABW + l * 8] =
            *(const uint4*)(h + (size_t)row * HD + l * 8);
    }
    __syncthreads();

    ffrag acc[2][4];
    for (int m = 0; m < 2; ++m)
        for (int n = 0; n < 4; ++n)
            acc[m][n] = (ffrag){0.f, 0.f, 0.f, 0.f};

    kloop_rot<16, 2>(acc, slab, Bswz + ((size_t)(w << 2) * 64 + l) * 8, ml, q);

    for (int m = 0; m < 2; ++m)
        for (int rr = 0; rr < 4; ++rr) {
            int grow = rowbase + 16 * m + 4 * q + rr;
            if (grow < N_NODES) {
                ushort4 v = make_ushort4(f2bf(acc[m][0][rr]), f2bf(acc[m][1][rr]),
                                         f2bf(acc[m][2][rr]), f2bf(acc[m][3][rr]));
                *(ushort4*)(out + (size_t)grow * HD + w * 64 + ml * 4) = v;
            }
        }
}

// ---------------- Fused edge MLP (64 edges x 512 cols per block) ------------
// acc = HAp[src] + HBp[dst] + LATBp[graph] (direct permuted loads);
// K-loop: 768 interleaved sin/cos (2 phases x 12 ktiles) with w1c;
// silu -> slab -> GEMM2(w2s) -> R8 two-half fp32 epilogue + 256-thread
// CSR segment reduce -> atomic agg.
__global__ __launch_bounds__(512, 4) void edge_mlp(
    const ushort* __restrict__ HAp,   const ushort* __restrict__ HBp,
    const float* __restrict__ LATBp,  const ushort* __restrict__ w1c,
    const ushort* __restrict__ w2s,   const float* __restrict__ b2,
    float* __restrict__ agg,
    const int* __restrict__ edge_index, const int* __restrict__ e2g,
    const float* __restrict__ frac_diff, const int* __restrict__ ebuf) {

    __shared__ __align__(16) ushort slab[64 * SLABW];     // 66560 B
    __shared__ int   ssrc[64];
    __shared__ int   sdst[64];
    __shared__ int   sgrp[64];
    __shared__ float sfd[64 * 3];

    const int t = threadIdx.x;        // 512 threads = 8 waves
    const int w = t >> 6;
    const int l = t & 63;
    const int q = l >> 4;
    const int ml = l & 15;
    const int rowbase = blockIdx.x * 64;

    if (t < 64) {
        int eid = ebuf[rowbase + t];
        ssrc[t] = edge_index[eid];
        sdst[t] = edge_index[N_EDGES + eid];
        sgrp[t] = e2g[eid];
        for (int c = 0; c < 3; ++c) sfd[t * 3 + c] = frac_diff[(size_t)eid * 3 + c];
    }
    __syncthreads();

    // ---- acc init: direct permuted loads (L2-hot) ----
    ffrag acc[4][4];
    {
        const int cb = w * 64 + ml * 4;
        for (int m = 0; m < 4; ++m)
            for (int rr = 0; rr < 4; ++rr) {
                int rowl = 16 * m + 4 * q + rr;
                ushort4 a4 = *(const ushort4*)(HAp + (size_t)ssrc[rowl] * HD + cb);
                ushort4 h4 = *(const ushort4*)(HBp + (size_t)sdst[rowl] * HD + cb);
                float4  l4 = *(const float4*)(LATBp + (size_t)sgrp[rowl] * HD + cb);
                acc[m][0][rr] = bf2f(a4.x) + bf2f(h4.x) + l4.x;
                acc[m][1][rr] = bf2f(a4.y) + bf2f(h4.y) + l4.y;
                acc[m][2][rr] = bf2f(a4.z) + bf2f(h4.z) + l4.z;
                acc[m][3][rr] = bf2f(a4.w) + bf2f(h4.w) + l4.w;
            }
    }

    const int r  = t >> 3;            // staging row 0..63
    const int c0 = (t & 7) * 4;       // staging col 0..28 step 4
    float fd3[3] = { sfd[r * 3 + 0], sfd[r * 3 + 1], sfd[r * 3 + 2] };

    // ---- sin/cos staging: cols = interleaved (sin_k, cos_k) pairs ----
    auto stage = [&](int phase) {
        for (int i = 0; i < 12; ++i) {
            int c = c0 + 32 * i;                 // 0..380
            int cp = phase * 384 + c;            // global C-col
            int d = cp >> 8;
            float x = fd3[d];
            int k0 = (cp & 255) >> 1;
            float f0 = (float)k0 * x;
            float f1 = f0 + x;
            float r0 = __builtin_amdgcn_fractf(f0);
            float r1 = __builtin_amdgcn_fractf(f1);
            union { __hip_bfloat162 h2[2]; ushort4 u4; } pk;
            pk.h2[0] = __float22bfloat162_rn(float2{__builtin_amdgcn_sinf(r0),
                                                    __builtin_amdgcn_cosf(r0)});
            pk.h2[1] = __float22bfloat162_rn(float2{__builtin_amdgcn_sinf(r1),
                                                    __builtin_amdgcn_cosf(r1)});
            *(ushort4*)&slab[r * SLABW + c] = pk.u4;
        }
    };

    const ushort* bpw1 = w1c + ((size_t)(w << 2) * 64 + l) * 8;
    const ushort* bpw2 = w2s + ((size_t)(w << 2) * 64 + l) * 8;

    stage(0);
    __syncthreads();
    kloop_rot<12, 4>(acc, slab, bpw1, ml, q);
    __syncthreads();
    stage(1);
    __syncthreads();
    kloop_rot<12, 4>(acc, slab, bpw1 + (size_t)12 * KSTR, ml, q);
    __syncthreads();

    // ---- e1 = silu(acc) -> slab (bf16, row-major); reset acc ----
    for (int n = 0; n < 4; ++n) {
        int cg = w * 64 + n * 16 + ml;
        for (int m = 0; m < 4; ++m)
            for (int rr = 0; rr < 4; ++rr) {
                int rowl = 16 * m + 4 * q + rr;
                slab[rowl * SLABW + cg] = f2bf(silu_f(acc[m][n][rr]));
            }
    }
    for (int m = 0; m < 4; ++m)
        for (int n = 0; n < 4; ++n)
            acc[m][n] = (ffrag){0.f, 0.f, 0.f, 0.f};
    __syncthreads();

    // ---- GEMM2 straight from the slab ----
    kloop_rot<16, 4>(acc, slab, bpw2, ml, q);

    // ---- silu + b2 + CSR run-length segment reduce -> atomic agg (R8) ----
    float* fs = (float*)slab;            // 64 x 256 fp32
    for (int hh = 0; hh < 2; ++hh) {
        __syncthreads();
        if ((w >> 2) == hh) {
            for (int n = 0; n < 4; ++n) {
                int cg = w * 64 + n * 16 + ml;
                int lc = cg - hh * 256;
                float bv = b2[cg];
                for (int m = 0; m < 4; ++m)
                    for (int rr = 0; rr < 4; ++rr) {
                        int rowl = 16 * m + 4 * q + rr;
                        fs[rowl * 256 + lc] = silu_f(acc[m][n][rr] + bv);
                    }
            }
        }
        __syncthreads();
        if (t < 256) {
            int col = hh * 256 + t;
            int cur = ssrc[0];
            float run = 0.f;
            for (int rr2 = 0; rr2 < 64; ++rr2) {
                int nd = ssrc[rr2];
                if (nd != cur) {
                    unsafeAtomicAdd(&agg[(size_t)cur * HD + col], run);
                    run = 0.f; cur = nd;
                }
                run += fs[rr2 * 256 + t];
            }
            unsafeAtomicAdd(&agg[(size_t)cur * HD + col], run);
        }
    }
}

// ---------------- Fused node MLP (64 nodes x 512 cols per block) ------------
__global__ __launch_bounds__(512, 4) void node_mlp(
    const ushort* __restrict__ h,     const ushort* __restrict__ aggb,
    const ushort* __restrict__ wn1s,  const ushort* __restrict__ wn2s,
    const float* __restrict__ b1,     const float* __restrict__ b2,
    const float* __restrict__ nf,     float* __restrict__ out) {

    __shared__ __align__(16) ushort slab[64 * SLABW];

    const int t = threadIdx.x;        // 512 threads = 8 waves
    const int w = t >> 6;
    const int l = t & 63;
    const int q = l >> 4;
    const int ml = l & 15;
    const int rowbase = blockIdx.x * 64;

    ffrag acc[4][4];
    for (int m = 0; m < 4; ++m)
        for (int n = 0; n < 4; ++n)
            acc[m][n] = (ffrag){0.f, 0.f, 0.f, 0.f};

    auto load_rows = [&](const ushort* base) {
        for (int j = 0; j < 8; ++j) {
            int rr = w * 8 + j;
            int row = rowbase + rr;
            if (row >= N_NODES) row = N_NODES - 1;
            *(uint4*)&slab[rr * SLABW + l * 8] =
                *(const uint4*)(base + (size_t)row * HD + l * 8);
        }
    };
    const ushort* bp1 = wn1s + ((size_t)(w << 2) * 64 + l) * 8;
    const ushort* bp2 = wn2s + ((size_t)(w << 2) * 64 + l) * 8;

    load_rows(h);                        __syncthreads();
    kloop_rot<16, 4>(acc, slab, bp1, ml, q);
    __syncthreads();
    load_rows(aggb);                     __syncthreads();
    kloop_rot<16, 4>(acc, slab, bp1 + (size_t)16 * KSTR, ml, q);
    __syncthreads();

    for (int n = 0; n < 4; ++n) {
        int cg = w * 64 + n * 16 + ml;
        float bv = b1[cg];
        for (int m = 0; m < 4; ++m)
            for (int rr = 0; rr < 4; ++rr) {
                int rowl = 16 * m + 4 * q + rr;
                slab[rowl * SLABW + cg] = f2bf(silu_f(acc[m][n][rr] + bv));
            }
    }
    for (int m = 0; m < 4; ++m)
        for (int n = 0; n < 4; ++n)
            acc[m][n] = (ffrag){0.f, 0.f, 0.f, 0.f};
    __syncthreads();

    kloop_rot<16, 4>(acc, slab, bp2, ml, q);

    for (int n = 0; n < 4; ++n) {
        int cg = w * 64 + n * 16 + ml;
        float bv = b2[cg];
        for (int m = 0; m < 4; ++m)
            for (int rr = 0; rr < 4; ++rr) {
                int rowl = 16 * m + 4 * q + rr;
                int row = rowbase + rowl;
                if (row < N_NODES) {
                    float v = silu_f(acc[m][n][rr] + bv);
                    out[(size_t)row * HD + cg] = nf[(size_t)row * HD + cg] + v;
                }
            }
    }
}

// ---------------------------------------------------------------------------
extern "C" void kernel_launch(void* const* d_in, const int* in_sizes, int n_in,
                              void* d_out, int out_size, void* d_ws, size_t ws_size,
                              hipStream_t stream) {
    const float* nf      = (const float*)d_in[0];
    const float* latt    = (const float*)d_in[1];
    const int*   eidx    = (const int*)d_in[2];
    const int*   e2g     = (const int*)d_in[3];
    const float* fd      = (const float*)d_in[4];
    const float* ln_g    = (const float*)d_in[6];
    const float* ln_b    = (const float*)d_in[7];
    const float* W_e1    = (const float*)d_in[8];
    const float* b_e1    = (const float*)d_in[9];
    const float* W_e2    = (const float*)d_in[10];
    const float* b_e2    = (const float*)d_in[11];
    const float* W_n1    = (const float*)d_in[12];
    const float* b_n1    = (const float*)d_in[13];
    const float* W_n2    = (const float*)d_in[14];
    const float* b_n2    = (const float*)d_in[15];
    float* out = (float*)d_out;

    auto al = [](size_t x) { return (x + 511) & ~(size_t)511; };
    size_t off_h    = 0;                         size_t sz_h    = (size_t)N_NODES * HD * 2;
    size_t off_w1a  = al(off_h + sz_h);          size_t sz_w1a  = (size_t)HD * HD * 2;
    size_t off_w1b  = al(off_w1a + sz_w1a);      size_t sz_w1b  = (size_t)HD * HD * 2;
    size_t off_w1c  = al(off_w1b + sz_w1b);      size_t sz_w1c  = (size_t)768 * HD * 2;
    size_t off_w2   = al(off_w1c + sz_w1c);      size_t sz_w2   = (size_t)HD * HD * 2;
    size_t off_wn1  = al(off_w2 + sz_w2);        size_t sz_wn1  = (size_t)2 * HD * HD * 2;
    size_t off_wn2  = al(off_wn1 + sz_wn1);      size_t sz_wn2  = (size_t)HD * HD * 2;
    size_t off_ha   = al(off_wn2 + sz_wn2);      size_t sz_ha   = (size_t)N_NODES * HD * 2;
    size_t off_hb   = al(off_ha + sz_ha);        size_t sz_hb   = (size_t)N_NODES * HD * 2;
    size_t off_lb   = al(off_hb + sz_hb);        size_t sz_lb   = (size_t)50 * HD * 4;
    size_t off_agb  = al(off_lb + sz_lb);        size_t sz_agb  = (size_t)N_NODES * HD * 2;
    size_t off_c32  = al(off_agb + sz_agb);      size_t sz_c32  = (size_t)N_NODES * 4;
    size_t off_cur  = al(off_c32 + sz_c32);      size_t sz_cur  = (size_t)N_NODES * 4;
    size_t off_rp   = al(off_cur + sz_cur);      size_t sz_rp   = (size_t)(N_NODES + 1) * 4;
    size_t off_ebuf = al(off_rp + sz_rp);        size_t sz_ebuf = (size_t)N_EDGES * 4;
    size_t off_agg  = al(off_ebuf + sz_ebuf);    size_t sz_agg  = (size_t)N_NODES * HD * 4;
    size_t need     = off_agg + sz_agg;

    if (ws_size < need) {
        sentinel_kernel<<<(out_size + 255) / 256, 256, 0, stream>>>(out, out_size);
        return;
    }

    char* ws = (char*)d_ws;
    ushort* h     = (ushort*)(ws + off_h);
    ushort* w1a_s = (ushort*)(ws + off_w1a);
    ushort* w1b_s = (ushort*)(ws + off_w1b);
    ushort* w1c_s = (ushort*)(ws + off_w1c);
    ushort* w2s   = (ushort*)(ws + off_w2);
    ushort* wn1s  = (ushort*)(ws + off_wn1);
    ushort* wn2s  = (ushort*)(ws + off_wn2);
    ushort* HAp   = (ushort*)(ws + off_ha);
    ushort* HBp   = (ushort*)(ws + off_hb);
    float*  LATBp = (float*)(ws + off_lb);
    ushort* aggb  = (ushort*)(ws + off_agb);
    int*    c32   = (int*)(ws + off_c32);
    int*    cur   = (int*)(ws + off_cur);
    int*    rp    = (int*)(ws + off_rp);
    int*    ebuf  = (int*)(ws + off_ebuf);
    float*  agg   = (float*)(ws + off_agg);

    // prep
    zero_kernel<<<(N_NODES * HD) / 256, 256, 0, stream>>>(c32, agg);
    wswz_kernel<<<(HD / 32) * NT * 64 / 256, 256, 0, stream>>>(W_e1, w1a_s, HD, 0);
    wswz_kernel<<<(HD / 32) * NT * 64 / 256, 256, 0, stream>>>(W_e1 + (size_t)HD * HD, w1b_s, HD, 0);
    wswz_kernel<<<(768 / 32) * NT * 64 / 256, 256, 0, stream>>>(W_e1, w1c_s, 768, 3);
    wswz_kernel<<<(HD / 32) * NT * 64 / 256, 256, 0, stream>>>(W_e2, w2s, HD, 0);
    wswz_kernel<<<(2 * HD / 32) * NT * 64 / 256, 256, 0, stream>>>(W_n1, wn1s, 2 * HD, 0);
    wswz_kernel<<<(HD / 32) * NT * 64 / 256, 256, 0, stream>>>(W_n2, wn2s, HD, 0);
    latb_kernel<<<50, 512, 0, stream>>>(latt, W_e1, b_e1, LATBp);

    // CSR build (edges sorted by src node)
    hist_kernel<<<(N_EDGES + 255) / 256, 256, 0, stream>>>(eidx, c32);
    scan_kernel<<<1, 1024, 0, stream>>>(c32, rp, cur);
    csr_fill<<<(N_EDGES + 255) / 256, 256, 0, stream>>>(eidx, cur, ebuf);

    // LN then node-level hoist (HAp, HBp)
    ln_kernel<<<N_NODES, 256, 0, stream>>>(nf, ln_g, ln_b, h);
    hab_gemm<<<dim3(313, 2), 512, 0, stream>>>(h, w1a_s, w1b_s, HAp, HBp);

    // fused edge MLP (CSR order) -> agg
    edge_mlp<<<N_EDGES / 64, 512, 0, stream>>>(
        HAp, HBp, LATBp, w1c_s, w2s, b_e2, agg, eidx, e2g, fd, ebuf);

    // scatter-mean divide (deg from CSR)
    aggdiv_kernel<<<(N_NODES * HD) / 256, 256, 0, stream>>>(agg, rp, aggb);

    // fused node MLP
    int nblocks = (N_NODES + 63) / 64;
    node_mlp<<<nblocks, 512, 0, stream>>>(h, aggb, wn1s, wn2s, b_n1, b_n2, nf, out);
}